// Round 2
// baseline (570.572 us; speedup 1.0000x reference)
//
#include <hip/hip_runtime.h>
#include <hip/hip_bf16.h>

typedef __attribute__((ext_vector_type(8))) short short8;
typedef __attribute__((ext_vector_type(4))) float f32x4;

#define NT 110592   // 48^3 tokens

static __device__ __forceinline__ float lo2f(unsigned int p){ unsigned int x = p << 16; float f; __builtin_memcpy(&f,&x,4); return f; }
static __device__ __forceinline__ float hi2f(unsigned int p){ unsigned int x = p & 0xffff0000u; float f; __builtin_memcpy(&f,&x,4); return f; }
static __device__ __forceinline__ unsigned int f2bf(float f){
  unsigned int x; __builtin_memcpy(&x,&f,4);
  x += 0x7fffu + ((x>>16)&1u);           // round-to-nearest-even
  return x >> 16;
}

// ------- weight convert+transpose: in fp32 [R][C] -> out bf16 [C][R] ---------
__global__ void tpose(const float* __restrict__ in, unsigned short* __restrict__ out,
                      int R, int Cc){
  int id = blockIdx.x*256 + threadIdx.x;
  if (id < R*Cc){ int r = id / Cc, c = id - r*Cc; out[c*R + r] = (unsigned short)f2bf(in[id]); }
}

// ---- MFMA GEMM: C[M][N] = A[M][K] * Bt[N][K]^T (+bias), bf16 compute --------
// AF32: A is fp32, converted to bf16 during LDS staging. Bt always bf16.
// CF32: C written fp32 with fp32 bias; else bf16, no bias.
// 128x128 tile, BK=32, 4 waves 2x2, each wave 64x64 via 4x4 MFMA 16x16x32.
// Fragment layouts (gfx950, verified): A/B: m|n = lane&15, k = (lane>>4)*8+j.
// C/D: col = lane&15, row = (lane>>4)*4 + reg.
template<bool AF32, bool CF32>
__global__ __launch_bounds__(256) void gemm_bt(
    const void* __restrict__ Av,
    const unsigned short* __restrict__ Bt,   // [N][K] bf16
    const float* __restrict__ bias,          // [N] fp32 (CF32 only)
    void* __restrict__ Cv,
    int M, int N, int K)
{
  __shared__ __align__(16) unsigned short As[128*40];  // stride 40: conflict-benign
  __shared__ __align__(16) unsigned short Bs[128*40];

  const int bm = blockIdx.x;
  const int bn = blockIdx.y;
  const int tid  = threadIdx.x;
  const int lane = tid & 63;
  const int wave = tid >> 6;
  const int wm = wave >> 1, wn = wave & 1;
  const int l16 = lane & 15, q = lane >> 4;

  f32x4 acc[4][4] = {};

  for (int k0 = 0; k0 < K; k0 += 32){
    __syncthreads();
    #pragma unroll
    for (int rep = 0; rep < 2; ++rep){
      int s = tid + rep*256;            // 512 slots: row = s>>2, grp = s&3 (8 elems)
      int row = s >> 2, grp = s & 3;
      if (AF32){
        const float* A = (const float*)Av;
        size_t base = (size_t)(bm*128 + row)*K + k0 + grp*8;
        float4 a0 = *(const float4*)&A[base];
        float4 a1 = *(const float4*)&A[base + 4];
        uint4 pk;
        pk.x = f2bf(a0.x) | (f2bf(a0.y) << 16);
        pk.y = f2bf(a0.z) | (f2bf(a0.w) << 16);
        pk.z = f2bf(a1.x) | (f2bf(a1.y) << 16);
        pk.w = f2bf(a1.z) | (f2bf(a1.w) << 16);
        *(uint4*)&As[row*40 + grp*8] = pk;
      } else {
        const unsigned short* A = (const unsigned short*)Av;
        float4 va = *(const float4*)&A[(size_t)(bm*128 + row)*K + k0 + grp*8];
        *(float4*)&As[row*40 + grp*8] = va;
      }
      float4 vb = *(const float4*)&Bt[(size_t)(bn*128 + row)*K + k0 + grp*8];
      *(float4*)&Bs[row*40 + grp*8] = vb;
    }
    __syncthreads();

    short8 af[4], bfm[4];
    #pragma unroll
    for (int t = 0; t < 4; ++t){
      af[t]  = *(const short8*)&As[(wm*64 + t*16 + l16)*40 + q*8];
      bfm[t] = *(const short8*)&Bs[(wn*64 + t*16 + l16)*40 + q*8];
    }
    #pragma unroll
    for (int im = 0; im < 4; ++im)
      #pragma unroll
      for (int in = 0; in < 4; ++in)
        acc[im][in] = __builtin_amdgcn_mfma_f32_16x16x32_bf16(af[im], bfm[in], acc[im][in], 0, 0, 0);
  }

  #pragma unroll
  for (int in = 0; in < 4; ++in){
    int col = bn*128 + wn*64 + in*16 + l16;
    float bv = CF32 ? bias[col] : 0.f;
    #pragma unroll
    for (int im = 0; im < 4; ++im){
      int row0 = bm*128 + wm*64 + im*16 + q*4;
      #pragma unroll
      for (int r = 0; r < 4; ++r){
        if (CF32) ((float*)Cv)[(size_t)(row0 + r)*N + col] = acc[im][in][r] + bv;
        else ((unsigned short*)Cv)[(size_t)(row0 + r)*N + col] = (unsigned short)f2bf(acc[im][in][r]);
      }
    }
  }
}

// ---------------- windowed attention with folded cyclic shift -----------------
// Output window (A,B,C): scores from shifted window (B,C,A) [einops mismatch],
// V and output from window (A,B,C). Masks: x iff B==11, y iff C==11, z iff A==11.
// All token coords +2 mod 48 (both rolls folded into indexing).
__global__ __launch_bounds__(64) void attn3d(
    const unsigned short* __restrict__ qkv,  // [NT][768] bf16: q|k|v each 256
    unsigned short* __restrict__ aout)       // [NT][256] bf16
{
  __shared__ __align__(16) float Ks[64*36];
  __shared__ __align__(16) float Vs[64*36];

  const int bid  = blockIdx.x;
  const int head = bid & 7;
  const int w    = bid >> 3;
  const int A  = w / 144;
  const int B  = (w / 12) % 12;
  const int Cw = w % 12;

  const int i  = threadIdx.x;          // token 0..63
  const int ix = i >> 4, iy = (i >> 2) & 3, iz = i & 3;

  int px = (4*B  + ix + 2) % 48;
  int py = (4*Cw + iy + 2) % 48;
  int pz = (4*A  + iz + 2) % 48;
  size_t t_qk = ((size_t)px*48 + py)*48 + pz;
  int vx = (4*A  + ix + 2) % 48;
  int vy = (4*B  + iy + 2) % 48;
  int vz = (4*Cw + iz + 2) % 48;
  size_t t_v = ((size_t)vx*48 + vy)*48 + vz;

  const unsigned short* qp = qkv + t_qk*768 + head*32;        // q
  const unsigned short* kp = qp + 256;                        // k
  const unsigned short* vp = qkv + t_v*768 + 512 + head*32;   // v

  float qf[32];
  #pragma unroll
  for (int u = 0; u < 4; ++u){
    uint4 qv = *(const uint4*)(qp + u*8);
    uint4 kv = *(const uint4*)(kp + u*8);
    uint4 vv = *(const uint4*)(vp + u*8);
    qf[u*8+0]=lo2f(qv.x); qf[u*8+1]=hi2f(qv.x); qf[u*8+2]=lo2f(qv.y); qf[u*8+3]=hi2f(qv.y);
    qf[u*8+4]=lo2f(qv.z); qf[u*8+5]=hi2f(qv.z); qf[u*8+6]=lo2f(qv.w); qf[u*8+7]=hi2f(qv.w);
    Ks[i*36+u*8+0]=lo2f(kv.x); Ks[i*36+u*8+1]=hi2f(kv.x); Ks[i*36+u*8+2]=lo2f(kv.y); Ks[i*36+u*8+3]=hi2f(kv.y);
    Ks[i*36+u*8+4]=lo2f(kv.z); Ks[i*36+u*8+5]=hi2f(kv.z); Ks[i*36+u*8+6]=lo2f(kv.w); Ks[i*36+u*8+7]=hi2f(kv.w);
    Vs[i*36+u*8+0]=lo2f(vv.x); Vs[i*36+u*8+1]=hi2f(vv.x); Vs[i*36+u*8+2]=lo2f(vv.y); Vs[i*36+u*8+3]=hi2f(vv.y);
    Vs[i*36+u*8+4]=lo2f(vv.z); Vs[i*36+u*8+5]=hi2f(vv.z); Vs[i*36+u*8+6]=lo2f(vv.w); Vs[i*36+u*8+7]=hi2f(vv.w);
  }
  __syncthreads();

  const float scale = 0.17677669529663687f;  // 32^-0.5
  const int mx = (B == 11), my = (Cw == 11), mz = (A == 11);
  const int ihx = ix >> 1, ihy = iy >> 1, ihz = iz >> 1;

  float S[64];
  #pragma unroll
  for (int j = 0; j < 64; ++j){
    const float* kr = &Ks[j*36];
    float s0=0.f, s1=0.f, s2=0.f, s3=0.f;
    #pragma unroll
    for (int u = 0; u < 8; ++u){
      float4 kv = *(const float4*)(kr + u*4);
      s0 += qf[u*4+0]*kv.x; s1 += qf[u*4+1]*kv.y;
      s2 += qf[u*4+2]*kv.z; s3 += qf[u*4+3]*kv.w;
    }
    float s = ((s0+s1)+(s2+s3)) * scale;
    int jhx = (j >> 5) & 1, jhy = (j >> 3) & 1, jhz = (j >> 1) & 1;
    int dead = (mx & (ihx ^ jhx)) | (my & (ihy ^ jhy)) | (mz & (ihz ^ jhz));
    S[j] = dead ? -1e30f : s;
  }

  float m = -3e38f;
  #pragma unroll
  for (int j = 0; j < 64; ++j) m = fmaxf(m, S[j]);
  float sum = 0.f;
  #pragma unroll
  for (int j = 0; j < 64; ++j){ float e = __expf(S[j] - m); S[j] = e; sum += e; }
  float inv = 1.f / sum;

  float O[32];
  #pragma unroll
  for (int d = 0; d < 32; ++d) O[d] = 0.f;
  #pragma unroll
  for (int j = 0; j < 64; ++j){
    float p = S[j];
    const float* vr = &Vs[j*36];
    #pragma unroll
    for (int u = 0; u < 8; ++u){
      float4 vv = *(const float4*)(vr + u*4);
      O[u*4+0] += p*vv.x; O[u*4+1] += p*vv.y; O[u*4+2] += p*vv.z; O[u*4+3] += p*vv.w;
    }
  }

  unsigned short* op = aout + t_v*256 + head*32;
  #pragma unroll
  for (int u = 0; u < 4; ++u){
    uint4 pk;
    pk.x = f2bf(O[u*8+0]*inv) | (f2bf(O[u*8+1]*inv) << 16);
    pk.y = f2bf(O[u*8+2]*inv) | (f2bf(O[u*8+3]*inv) << 16);
    pk.z = f2bf(O[u*8+4]*inv) | (f2bf(O[u*8+5]*inv) << 16);
    pk.w = f2bf(O[u*8+6]*inv) | (f2bf(O[u*8+7]*inv) << 16);
    *(uint4*)(op + u*8) = pk;
  }
}

// ------------------------------- launch ---------------------------------------
extern "C" void kernel_launch(void* const* d_in, const int* in_sizes, int n_in,
                              void* d_out, int out_size, void* d_ws, size_t ws_size,
                              hipStream_t stream) {
  const float* x     = (const float*)d_in[0];  // [NT][256] fp32
  const float* w_qkv = (const float*)d_in[1];  // [256][768] fp32
  const float* w_out = (const float*)d_in[2];  // [256][256] fp32
  const float* b_out = (const float*)d_in[3];  // [256] fp32
  float* out = (float*)d_out;                  // [NT][256] fp32

  unsigned short* qkv   = (unsigned short*)d_ws;                 // NT*768 bf16
  unsigned short* aout  = qkv   + (size_t)NT*768;                // NT*256 bf16
  unsigned short* wqkvT = aout  + (size_t)NT*256;                // 768*256 bf16
  unsigned short* woutT = wqkvT + (size_t)768*256;               // 256*256 bf16
  // total ws use: ~227 MB

  tpose<<<dim3((256*768 + 255)/256), dim3(256), 0, stream>>>(w_qkv, wqkvT, 256, 768);
  tpose<<<dim3((256*256 + 255)/256), dim3(256), 0, stream>>>(w_out, woutT, 256, 256);

  gemm_bt<true,  false><<<dim3(NT/128, 768/128), dim3(256), 0, stream>>>(x, wqkvT, nullptr, qkv, NT, 768, 256);

  attn3d<<<dim3(1728*8), dim3(64), 0, stream>>>(qkv, aout);

  gemm_bt<false, true><<<dim3(NT/128, 256/128), dim3(256), 0, stream>>>(aout, woutT, b_out, out, NT, 256, 256);
}

// Round 3
// 388.281 us; speedup vs baseline: 1.4695x; 1.4695x over previous
//
#include <hip/hip_runtime.h>
#include <hip/hip_bf16.h>

typedef __attribute__((ext_vector_type(8))) short short8;
typedef __attribute__((ext_vector_type(4))) float f32x4;

#define NT 110592   // 48^3 tokens

static __device__ __forceinline__ unsigned int f2bf(float f){
  unsigned int x; __builtin_memcpy(&x,&f,4);
  x += 0x7fffu + ((x>>16)&1u);           // round-to-nearest-even
  return x >> 16;
}

static __device__ __forceinline__ void gll16(const unsigned short* g, unsigned short* l){
  typedef const __attribute__((address_space(1))) unsigned int gu32;
  typedef __attribute__((address_space(3))) unsigned int lu32;
  __builtin_amdgcn_global_load_lds((gu32*)(const void*)g, (lu32*)(void*)l, 16, 0, 0);
}

// ---------- x fp32 -> bf16, 8 elems/thread ----------
__global__ void xconv(const float* __restrict__ x, unsigned short* __restrict__ o){
  size_t i = ((size_t)blockIdx.x*256 + threadIdx.x) * 8;
  float4 a = *(const float4*)(x+i), b = *(const float4*)(x+i+4);
  uint4 pk;
  pk.x = f2bf(a.x)|(f2bf(a.y)<<16); pk.y = f2bf(a.z)|(f2bf(a.w)<<16);
  pk.z = f2bf(b.x)|(f2bf(b.y)<<16); pk.w = f2bf(b.z)|(f2bf(b.w)<<16);
  *(uint4*)(o+i) = pk;
}

// ---------- weight convert+transpose: fp32 [R][C] -> bf16 [C][R] ----------
__global__ void tpose(const float* __restrict__ in, unsigned short* __restrict__ out,
                      int R, int Cc){
  int id = blockIdx.x*256 + threadIdx.x;
  if (id < R*Cc){ int r = id / Cc, c = id - r*Cc; out[c*R + r] = (unsigned short)f2bf(in[id]); }
}

// ---------- MFMA GEMM: C[M][N] = A[M][K]*Bt[N][K]^T (+bias), bf16 in ----------
// 128x128 tile, BK=32, global_load_lds width 16, XOR-swizzled LDS layout.
// Slot s (0..511): row=s>>2, memory col-group g=(s&3)^((s>>3)&3); LDS off s*16B.
// Fragment read for logical (row,g): elem off row*32 + (g^((row>>1)&3))*8.
template<bool CF32>
__global__ __launch_bounds__(256) void gemm_bt(
    const unsigned short* __restrict__ A,    // [M][K] bf16
    const unsigned short* __restrict__ Bt,   // [N][K] bf16
    const float* __restrict__ bias,          // [N] fp32 (CF32 only)
    void* __restrict__ Cv,
    int M, int N, int K)
{
  __shared__ __align__(16) unsigned short As[128*32];
  __shared__ __align__(16) unsigned short Bs[128*32];

  const int bm = blockIdx.x, bn = blockIdx.y;
  const int tid  = threadIdx.x;
  const int lane = tid & 63;
  const int wave = tid >> 6;
  const int wm = wave >> 1, wn = wave & 1;
  const int l16 = lane & 15, q = lane >> 4;

  const size_t arow0 = (size_t)(bm*128 + (tid>>2))*K;
  const size_t brow0 = (size_t)(bn*128 + (tid>>2))*K;
  const int g8  = ((tid&3) ^ ((tid>>3)&3)) * 8;   // swizzled memory col for staging
  const int cg8 = (q ^ ((l16>>1)&3)) * 8;         // swizzled LDS col for frag reads

  f32x4 acc[4][4] = {};

  for (int k0 = 0; k0 < K; k0 += 32){
    __syncthreads();
    gll16(A  + arow0 + k0 + g8,                 &As[tid*8]);
    gll16(A  + arow0 + (size_t)64*K + k0 + g8,  &As[(tid+256)*8]);
    gll16(Bt + brow0 + k0 + g8,                 &Bs[tid*8]);
    gll16(Bt + brow0 + (size_t)64*K + k0 + g8,  &Bs[(tid+256)*8]);
    __syncthreads();

    short8 af[4], bfm[4];
    #pragma unroll
    for (int t = 0; t < 4; ++t){
      af[t]  = *(const short8*)&As[(wm*64 + t*16 + l16)*32 + cg8];
      bfm[t] = *(const short8*)&Bs[(wn*64 + t*16 + l16)*32 + cg8];
    }
    #pragma unroll
    for (int im = 0; im < 4; ++im)
      #pragma unroll
      for (int in = 0; in < 4; ++in)
        acc[im][in] = __builtin_amdgcn_mfma_f32_16x16x32_bf16(af[im], bfm[in], acc[im][in], 0, 0, 0);
  }

  #pragma unroll
  for (int in = 0; in < 4; ++in){
    int col = bn*128 + wn*64 + in*16 + l16;
    float bv = CF32 ? bias[col] : 0.f;
    #pragma unroll
    for (int im = 0; im < 4; ++im){
      int row0 = bm*128 + wm*64 + im*16 + q*4;
      #pragma unroll
      for (int r = 0; r < 4; ++r){
        if (CF32) ((float*)Cv)[(size_t)(row0 + r)*N + col] = acc[im][in][r] + bv;
        else ((unsigned short*)Cv)[(size_t)(row0 + r)*N + col] = (unsigned short)f2bf(acc[im][in][r]);
      }
    }
  }
}

// ---------- MFMA windowed attention, 1 wave per (window,head), no barriers ----
// S^T = K·Q^T via mfma (rows j, cols i); softmax over j = per-lane sum + 2 shfl;
// P -> LDS (bf16) -> B-frags; V^T staged in LDS; O^T = V^T·P^T via mfma.
// Window map (verified R2): scores window (B,C,A), V/out window (A,B,C),
// masks x|B==11, y|C==11, z|A==11; all coords +2 mod 48 (both rolls folded).
__global__ __launch_bounds__(256) void attn3d(
    const unsigned short* __restrict__ qkv,  // [NT][768] bf16: q|k|v
    unsigned short* __restrict__ aout)       // [NT][256] bf16
{
  __shared__ __align__(16) unsigned short sh[4*6912];   // per wave: P[64][72] + VT[32][72]
  const int tid  = threadIdx.x;
  const int wave = tid >> 6, lane = tid & 63;
  const int l16  = lane & 15, q = lane >> 4;
  unsigned short* P  = sh + wave*6912;
  unsigned short* VT = P + 64*72;

  const int wh   = blockIdx.x*4 + wave;
  const int head = wh & 7;
  const int w    = wh >> 3;
  const int A  = w / 144;
  const int B  = (w / 12) % 12;
  const int Cw = w % 12;

  const int iyy = l16 >> 2, izz = l16 & 3;
  int tok_qk[4], tok_v[4];
  #pragma unroll
  for (int t = 0; t < 4; ++t){
    int px = (4*B  + t   + 2) % 48;
    int py = (4*Cw + iyy + 2) % 48;
    int pz = (4*A  + izz + 2) % 48;
    tok_qk[t] = (px*48 + py)*48 + pz;
    int vx = (4*A  + t   + 2) % 48;
    int vy = (4*B  + iyy + 2) % 48;
    int vz = (4*Cw + izz + 2) % 48;
    tok_v[t] = (vx*48 + vy)*48 + vz;
  }

  // stage V^T: lane = token idx, 32 dims -> scalar b16 writes (2-way free)
  {
    int sx = (4*A  + (lane>>4)     + 2) % 48;
    int sy = (4*B  + ((lane>>2)&3) + 2) % 48;
    int sz = (4*Cw + (lane&3)      + 2) % 48;
    const unsigned short* vp = qkv + (size_t)((sx*48+sy)*48+sz)*768 + 512 + head*32;
    uint4 v0 = *(const uint4*)(vp);
    uint4 v1 = *(const uint4*)(vp+8);
    uint4 v2 = *(const uint4*)(vp+16);
    uint4 v3 = *(const uint4*)(vp+24);
    unsigned vv[16] = {v0.x,v0.y,v0.z,v0.w, v1.x,v1.y,v1.z,v1.w,
                       v2.x,v2.y,v2.z,v2.w, v3.x,v3.y,v3.z,v3.w};
    #pragma unroll
    for (int u = 0; u < 16; ++u){
      VT[(2*u+0)*72 + lane] = (unsigned short)(vv[u] & 0xffffu);
      VT[(2*u+1)*72 + lane] = (unsigned short)(vv[u] >> 16);
    }
  }

  // K/Q fragments straight from global (A/B layout: m|n=l16, k=q*8+j)
  short8 kf[4], qf[4];
  #pragma unroll
  for (int t = 0; t < 4; ++t){
    const unsigned short* base = qkv + (size_t)tok_qk[t]*768 + head*32 + q*8;
    qf[t] = *(const short8*)(base);
    kf[t] = *(const short8*)(base + 256);
  }

  f32x4 s[4][4] = {};
  #pragma unroll
  for (int im = 0; im < 4; ++im)
    #pragma unroll
    for (int jn = 0; jn < 4; ++jn)
      s[im][jn] = __builtin_amdgcn_mfma_f32_16x16x32_bf16(kf[im], qf[jn], s[im][jn], 0, 0, 0);

  // scale + mask + exp (no max-sub: |s|<~8), pack P to LDS, row sums
  const float scale = 0.17677669529663687f;
  const int mx = (B == 11), my = (Cw == 11), mz = (A == 11);
  const int dy = my & ((q>>1) ^ (l16>>3));
  float sum4[4] = {0.f,0.f,0.f,0.f};
  #pragma unroll
  for (int jn = 0; jn < 4; ++jn){
    #pragma unroll
    for (int im = 0; im < 4; ++im){
      const int dxy = (mx & ((im>>1) ^ (jn>>1))) | dy;
      float e0 = (dxy | (mz & (0 ^ ((l16>>1)&1)))) ? 0.f : __expf(s[im][jn][0]*scale);
      float e1 = (dxy | (mz & (0 ^ ((l16>>1)&1)))) ? 0.f : __expf(s[im][jn][1]*scale);
      float e2 = (dxy | (mz & (1 ^ ((l16>>1)&1)))) ? 0.f : __expf(s[im][jn][2]*scale);
      float e3 = (dxy | (mz & (1 ^ ((l16>>1)&1)))) ? 0.f : __expf(s[im][jn][3]*scale);
      sum4[jn] += (e0+e1)+(e2+e3);
      uint2 pk;
      pk.x = f2bf(e0) | (f2bf(e1)<<16);
      pk.y = f2bf(e2) | (f2bf(e3)<<16);
      *(uint2*)&P[(jn*16+l16)*72 + im*16 + q*4] = pk;   // row i, cols j..j+3
    }
  }
  #pragma unroll
  for (int jn = 0; jn < 4; ++jn){
    float sj = sum4[jn];
    sj += __shfl_xor(sj, 16);
    sj += __shfl_xor(sj, 32);
    sum4[jn] = 1.f / sj;
  }

  // O^T = V^T · P^T  (M=32 d, N=64 i, K=64 j)
  f32x4 o[2][4] = {};
  #pragma unroll
  for (int ks = 0; ks < 2; ++ks){
    short8 vf[2], pf[4];
    #pragma unroll
    for (int dt = 0; dt < 2; ++dt)
      vf[dt] = *(const short8*)&VT[(dt*16 + l16)*72 + ks*32 + q*8];
    #pragma unroll
    for (int it = 0; it < 4; ++it)
      pf[it] = *(const short8*)&P[(it*16 + l16)*72 + ks*32 + q*8];
    #pragma unroll
    for (int dt = 0; dt < 2; ++dt)
      #pragma unroll
      for (int it = 0; it < 4; ++it)
        o[dt][it] = __builtin_amdgcn_mfma_f32_16x16x32_bf16(vf[dt], pf[it], o[dt][it], 0, 0, 0);
  }

  // epilogue: O^T[d=dt*16+q*4+r][i=it*16+l16] * inv[it] -> aout[tok_v(i)]
  #pragma unroll
  for (int it = 0; it < 4; ++it){
    float inv = sum4[it];
    unsigned short* op = aout + (size_t)tok_v[it]*256 + head*32;
    #pragma unroll
    for (int dt = 0; dt < 2; ++dt){
      uint2 pk;
      pk.x = f2bf(o[dt][it][0]*inv) | (f2bf(o[dt][it][1]*inv) << 16);
      pk.y = f2bf(o[dt][it][2]*inv) | (f2bf(o[dt][it][3]*inv) << 16);
      *(uint2*)(op + dt*16 + q*4) = pk;
    }
  }
}

// ------------------------------- launch ---------------------------------------
extern "C" void kernel_launch(void* const* d_in, const int* in_sizes, int n_in,
                              void* d_out, int out_size, void* d_ws, size_t ws_size,
                              hipStream_t stream) {
  const float* x     = (const float*)d_in[0];  // [NT][256] fp32
  const float* w_qkv = (const float*)d_in[1];  // [256][768] fp32
  const float* w_out = (const float*)d_in[2];  // [256][256] fp32
  const float* b_out = (const float*)d_in[3];  // [256] fp32
  float* out = (float*)d_out;                  // [NT][256] fp32

  unsigned short* qkv   = (unsigned short*)d_ws;                 // NT*768 bf16
  unsigned short* xbf   = qkv   + (size_t)NT*768;                // NT*256 bf16 (aliases aout)
  unsigned short* aout  = xbf;                                   // reused after GEMM1
  unsigned short* wqkvT = xbf   + (size_t)NT*256;                // 768*256 bf16
  unsigned short* woutT = wqkvT + (size_t)768*256;               // 256*256 bf16
  // total ws use ≈ 227 MB (same as validated round-2 layout)

  xconv<<<dim3(NT*256/2048), dim3(256), 0, stream>>>(x, xbf);
  tpose<<<dim3((256*768 + 255)/256), dim3(256), 0, stream>>>(w_qkv, wqkvT, 256, 768);
  tpose<<<dim3((256*256 + 255)/256), dim3(256), 0, stream>>>(w_out, woutT, 256, 256);

  gemm_bt<false><<<dim3(NT/128, 768/128), dim3(256), 0, stream>>>(xbf, wqkvT, nullptr, qkv, NT, 768, 256);

  attn3d<<<dim3(13824/4), dim3(256), 0, stream>>>(qkv, aout);

  gemm_bt<true><<<dim3(NT/128, 256/128), dim3(256), 0, stream>>>(aout, woutT, b_out, out, NT, 256, 256);
}

// Round 4
// 386.367 us; speedup vs baseline: 1.4768x; 1.0050x over previous
//
#include <hip/hip_runtime.h>
#include <hip/hip_bf16.h>

typedef __attribute__((ext_vector_type(8))) short short8;
typedef __attribute__((ext_vector_type(4))) float f32x4;

#define NT 110592   // 48^3 tokens

static __device__ __forceinline__ unsigned int f2bf(float f){
  unsigned int x; __builtin_memcpy(&x,&f,4);
  x += 0x7fffu + ((x>>16)&1u);           // round-to-nearest-even
  return x >> 16;
}

static __device__ __forceinline__ void gll16(const unsigned short* g, unsigned short* l){
  typedef const __attribute__((address_space(1))) unsigned int gu32;
  typedef __attribute__((address_space(3))) unsigned int lu32;
  __builtin_amdgcn_global_load_lds((gu32*)(const void*)g, (lu32*)(void*)l, 16, 0, 0);
}

// ---------- x fp32 -> bf16, 8 elems/thread ----------
__global__ void xconv(const float* __restrict__ x, unsigned short* __restrict__ o){
  size_t i = ((size_t)blockIdx.x*256 + threadIdx.x) * 8;
  float4 a = *(const float4*)(x+i), b = *(const float4*)(x+i+4);
  uint4 pk;
  pk.x = f2bf(a.x)|(f2bf(a.y)<<16); pk.y = f2bf(a.z)|(f2bf(a.w)<<16);
  pk.z = f2bf(b.x)|(f2bf(b.y)<<16); pk.w = f2bf(b.z)|(f2bf(b.w)<<16);
  *(uint4*)(o+i) = pk;
}

// ---------- weight convert+transpose: fp32 [R][C] -> bf16 [C][R] ----------
__global__ void tpose(const float* __restrict__ in, unsigned short* __restrict__ out,
                      int R, int Cc){
  int id = blockIdx.x*256 + threadIdx.x;
  if (id < R*Cc){ int r = id / Cc, c = id - r*Cc; out[c*R + r] = (unsigned short)f2bf(in[id]); }
}

// ---------- MFMA GEMM: C[M][N] = A[M][K]*Bt[N][K]^T (+bias), bf16 in ----------
// 128x128 tile, BK=64 (two 32-halves), global_load_lds w16, XOR-swizzled LDS.
// Grid: (N/128 fastest, M/128) so consecutive blocks share the A row-strip.
// Per 32-half: slot s(0..511): row=s>>2, mem col-group g=(s&3)^((s>>3)&3).
// Fragment read (row, lane): elem off row*32 + ((q^((l16>>1)&3))*8.
template<bool CF32>
__global__ __launch_bounds__(256) void gemm_bt(
    const unsigned short* __restrict__ A,    // [M][K] bf16
    const unsigned short* __restrict__ Bt,   // [N][K] bf16
    const float* __restrict__ bias,          // [N] fp32 (CF32 only)
    void* __restrict__ Cv,
    int M, int N, int K)
{
  __shared__ __align__(16) unsigned short As[2*128*32];  // 16 KB: two 32-wide halves
  __shared__ __align__(16) unsigned short Bs[2*128*32];

  const int bn = blockIdx.x, bm = blockIdx.y;   // bn fastest: A-strip L2/L3 reuse
  const int tid  = threadIdx.x;
  const int lane = tid & 63;
  const int wave = tid >> 6;
  const int wm = wave >> 1, wn = wave & 1;
  const int l16 = lane & 15, q = lane >> 4;

  const size_t arow0 = (size_t)(bm*128 + (tid>>2))*K;
  const size_t brow0 = (size_t)(bn*128 + (tid>>2))*K;
  const int g8  = ((tid&3) ^ ((tid>>3)&3)) * 8;   // swizzled memory col for staging
  const int cg8 = (q ^ ((l16>>1)&3)) * 8;         // swizzled LDS col for frag reads

  f32x4 acc[4][4] = {};

  for (int k0 = 0; k0 < K; k0 += 64){
    __syncthreads();
    gll16(A  + arow0 + k0 + g8,                      &As[tid*8]);
    gll16(A  + arow0 + (size_t)64*K + k0 + g8,       &As[(tid+256)*8]);
    gll16(A  + arow0 + k0 + 32 + g8,                 &As[4096 + tid*8]);
    gll16(A  + arow0 + (size_t)64*K + k0 + 32 + g8,  &As[4096 + (tid+256)*8]);
    gll16(Bt + brow0 + k0 + g8,                      &Bs[tid*8]);
    gll16(Bt + brow0 + (size_t)64*K + k0 + g8,       &Bs[(tid+256)*8]);
    gll16(Bt + brow0 + k0 + 32 + g8,                 &Bs[4096 + tid*8]);
    gll16(Bt + brow0 + (size_t)64*K + k0 + 32 + g8,  &Bs[4096 + (tid+256)*8]);
    __syncthreads();

    #pragma unroll
    for (int h = 0; h < 2; ++h){
      short8 af[4], bfm[4];
      #pragma unroll
      for (int t = 0; t < 4; ++t){
        af[t]  = *(const short8*)&As[h*4096 + (wm*64 + t*16 + l16)*32 + cg8];
        bfm[t] = *(const short8*)&Bs[h*4096 + (wn*64 + t*16 + l16)*32 + cg8];
      }
      #pragma unroll
      for (int im = 0; im < 4; ++im)
        #pragma unroll
        for (int in = 0; in < 4; ++in)
          acc[im][in] = __builtin_amdgcn_mfma_f32_16x16x32_bf16(af[im], bfm[in], acc[im][in], 0, 0, 0);
    }
  }

  #pragma unroll
  for (int in = 0; in < 4; ++in){
    int col = bn*128 + wn*64 + in*16 + l16;
    float bv = CF32 ? bias[col] : 0.f;
    #pragma unroll
    for (int im = 0; im < 4; ++im){
      int row0 = bm*128 + wm*64 + im*16 + q*4;
      #pragma unroll
      for (int r = 0; r < 4; ++r){
        if (CF32) ((float*)Cv)[(size_t)(row0 + r)*N + col] = acc[im][in][r] + bv;
        else ((unsigned short*)Cv)[(size_t)(row0 + r)*N + col] = (unsigned short)f2bf(acc[im][in][r]);
      }
    }
  }
}

// ---------- MFMA windowed attention, 1 wave per (window,head), no barriers ----
// S^T = K·Q^T via mfma (rows j, cols i); softmax over j = per-lane sum + 2 shfl;
// P -> LDS (bf16) -> B-frags; V^T staged in LDS; O^T = V^T·P^T via mfma.
// Window map (verified R2): scores window (B,C,A), V/out window (A,B,C),
// masks x|B==11, y|C==11, z|A==11; all coords +2 mod 48 (both rolls folded).
__global__ __launch_bounds__(256) void attn3d(
    const unsigned short* __restrict__ qkv,  // [NT][768] bf16: q|k|v
    unsigned short* __restrict__ aout)       // [NT][256] bf16
{
  __shared__ __align__(16) unsigned short sh[4*6912];   // per wave: P[64][72] + VT[32][72]
  const int tid  = threadIdx.x;
  const int wave = tid >> 6, lane = tid & 63;
  const int l16  = lane & 15, q = lane >> 4;
  unsigned short* P  = sh + wave*6912;
  unsigned short* VT = P + 64*72;

  const int wh   = blockIdx.x*4 + wave;
  const int head = wh & 7;
  const int w    = wh >> 3;
  const int A  = w / 144;
  const int B  = (w / 12) % 12;
  const int Cw = w % 12;

  const int iyy = l16 >> 2, izz = l16 & 3;
  int tok_qk[4], tok_v[4];
  #pragma unroll
  for (int t = 0; t < 4; ++t){
    int px = (4*B  + t   + 2) % 48;
    int py = (4*Cw + iyy + 2) % 48;
    int pz = (4*A  + izz + 2) % 48;
    tok_qk[t] = (px*48 + py)*48 + pz;
    int vx = (4*A  + t   + 2) % 48;
    int vy = (4*B  + iyy + 2) % 48;
    int vz = (4*Cw + izz + 2) % 48;
    tok_v[t] = (vx*48 + vy)*48 + vz;
  }

  // stage V^T: lane = token idx, 32 dims -> scalar b16 writes (2-way free)
  {
    int sx = (4*A  + (lane>>4)     + 2) % 48;
    int sy = (4*B  + ((lane>>2)&3) + 2) % 48;
    int sz = (4*Cw + (lane&3)      + 2) % 48;
    const unsigned short* vp = qkv + (size_t)((sx*48+sy)*48+sz)*768 + 512 + head*32;
    uint4 v0 = *(const uint4*)(vp);
    uint4 v1 = *(const uint4*)(vp+8);
    uint4 v2 = *(const uint4*)(vp+16);
    uint4 v3 = *(const uint4*)(vp+24);
    unsigned vv[16] = {v0.x,v0.y,v0.z,v0.w, v1.x,v1.y,v1.z,v1.w,
                       v2.x,v2.y,v2.z,v2.w, v3.x,v3.y,v3.z,v3.w};
    #pragma unroll
    for (int u = 0; u < 16; ++u){
      VT[(2*u+0)*72 + lane] = (unsigned short)(vv[u] & 0xffffu);
      VT[(2*u+1)*72 + lane] = (unsigned short)(vv[u] >> 16);
    }
  }

  // K/Q fragments straight from global (A/B layout: m|n=l16, k=q*8+j)
  short8 kf[4], qf[4];
  #pragma unroll
  for (int t = 0; t < 4; ++t){
    const unsigned short* base = qkv + (size_t)tok_qk[t]*768 + head*32 + q*8;
    qf[t] = *(const short8*)(base);
    kf[t] = *(const short8*)(base + 256);
  }

  f32x4 s[4][4] = {};
  #pragma unroll
  for (int im = 0; im < 4; ++im)
    #pragma unroll
    for (int jn = 0; jn < 4; ++jn)
      s[im][jn] = __builtin_amdgcn_mfma_f32_16x16x32_bf16(kf[im], qf[jn], s[im][jn], 0, 0, 0);

  // scale + mask + exp (no max-sub: |s|<~8), pack P to LDS, row sums
  const float scale = 0.17677669529663687f;
  const int mx = (B == 11), my = (Cw == 11), mz = (A == 11);
  const int dy = my & ((q>>1) ^ (l16>>3));
  float sum4[4] = {0.f,0.f,0.f,0.f};
  #pragma unroll
  for (int jn = 0; jn < 4; ++jn){
    #pragma unroll
    for (int im = 0; im < 4; ++im){
      const int dxy = (mx & ((im>>1) ^ (jn>>1))) | dy;
      float e0 = (dxy | (mz & (0 ^ ((l16>>1)&1)))) ? 0.f : __expf(s[im][jn][0]*scale);
      float e1 = (dxy | (mz & (0 ^ ((l16>>1)&1)))) ? 0.f : __expf(s[im][jn][1]*scale);
      float e2 = (dxy | (mz & (1 ^ ((l16>>1)&1)))) ? 0.f : __expf(s[im][jn][2]*scale);
      float e3 = (dxy | (mz & (1 ^ ((l16>>1)&1)))) ? 0.f : __expf(s[im][jn][3]*scale);
      sum4[jn] += (e0+e1)+(e2+e3);
      uint2 pk;
      pk.x = f2bf(e0) | (f2bf(e1)<<16);
      pk.y = f2bf(e2) | (f2bf(e3)<<16);
      *(uint2*)&P[(jn*16+l16)*72 + im*16 + q*4] = pk;   // row i, cols j..j+3
    }
  }
  #pragma unroll
  for (int jn = 0; jn < 4; ++jn){
    float sj = sum4[jn];
    sj += __shfl_xor(sj, 16);
    sj += __shfl_xor(sj, 32);
    sum4[jn] = 1.f / sj;
  }

  // O^T = V^T · P^T  (M=32 d, N=64 i, K=64 j)
  f32x4 o[2][4] = {};
  #pragma unroll
  for (int ks = 0; ks < 2; ++ks){
    short8 vf[2], pf[4];
    #pragma unroll
    for (int dt = 0; dt < 2; ++dt)
      vf[dt] = *(const short8*)&VT[(dt*16 + l16)*72 + ks*32 + q*8];
    #pragma unroll
    for (int it = 0; it < 4; ++it)
      pf[it] = *(const short8*)&P[(it*16 + l16)*72 + ks*32 + q*8];
    #pragma unroll
    for (int dt = 0; dt < 2; ++dt)
      #pragma unroll
      for (int it = 0; it < 4; ++it)
        o[dt][it] = __builtin_amdgcn_mfma_f32_16x16x32_bf16(vf[dt], pf[it], o[dt][it], 0, 0, 0);
  }

  // epilogue: O^T[d=dt*16+q*4+r][i=it*16+l16] * inv[it] -> aout[tok_v(i)]
  #pragma unroll
  for (int it = 0; it < 4; ++it){
    float inv = sum4[it];
    unsigned short* op = aout + (size_t)tok_v[it]*256 + head*32;
    #pragma unroll
    for (int dt = 0; dt < 2; ++dt){
      uint2 pk;
      pk.x = f2bf(o[dt][it][0]*inv) | (f2bf(o[dt][it][1]*inv) << 16);
      pk.y = f2bf(o[dt][it][2]*inv) | (f2bf(o[dt][it][3]*inv) << 16);
      *(uint2*)(op + dt*16 + q*4) = pk;
    }
  }
}

// ------------------------------- launch ---------------------------------------
extern "C" void kernel_launch(void* const* d_in, const int* in_sizes, int n_in,
                              void* d_out, int out_size, void* d_ws, size_t ws_size,
                              hipStream_t stream) {
  const float* x     = (const float*)d_in[0];  // [NT][256] fp32
  const float* w_qkv = (const float*)d_in[1];  // [256][768] fp32
  const float* w_out = (const float*)d_in[2];  // [256][256] fp32
  const float* b_out = (const float*)d_in[3];  // [256] fp32
  float* out = (float*)d_out;                  // [NT][256] fp32

  unsigned short* qkv   = (unsigned short*)d_ws;                 // NT*768 bf16
  unsigned short* xbf   = qkv   + (size_t)NT*768;                // NT*256 bf16 (aliases aout)
  unsigned short* aout  = xbf;                                   // reused after GEMM1
  unsigned short* wqkvT = xbf   + (size_t)NT*256;                // 768*256 bf16
  unsigned short* woutT = wqkvT + (size_t)768*256;               // 256*256 bf16
  // total ws use ≈ 227 MB

  xconv<<<dim3(NT*256/2048), dim3(256), 0, stream>>>(x, xbf);
  tpose<<<dim3((256*768 + 255)/256), dim3(256), 0, stream>>>(w_qkv, wqkvT, 256, 768);
  tpose<<<dim3((256*256 + 255)/256), dim3(256), 0, stream>>>(w_out, woutT, 256, 256);

  // grid: N-strips fastest -> consecutive blocks reuse the same A row-strip
  gemm_bt<false><<<dim3(768/128, NT/128), dim3(256), 0, stream>>>(xbf, wqkvT, nullptr, qkv, NT, 768, 256);

  attn3d<<<dim3(13824/4), dim3(256), 0, stream>>>(qkv, aout);

  gemm_bt<true><<<dim3(256/128, NT/128), dim3(256), 0, stream>>>(aout, woutT, b_out, out, NT, 256, 256);
}